// Round 4
// baseline (449.490 us; speedup 1.0000x reference)
//
#include <hip/hip_runtime.h>
#include <hip/hip_bf16.h>

typedef unsigned short u16;
typedef __attribute__((ext_vector_type(8))) short short8;   // 8 x bf16 bits = 4 VGPRs
typedef __attribute__((ext_vector_type(4))) float f32x4;

#define B_    4
#define L_    8192
#define C_    256
#define BL_   (B_*L_)
#define BLC_  (BL_*C_)
#define FFN_  2048
#define KCAT_ 512
#define EPS_  1e-5f

#define GLDS(dst, src) __builtin_amdgcn_global_load_lds( \
    (const __attribute__((address_space(1))) unsigned int*)(src), \
    (__attribute__((address_space(3))) unsigned int*)(dst), 16, 0, 0)

__device__ __forceinline__ float bf2f(u16 v) {
  union { unsigned int u; float f; } x; x.u = ((unsigned int)v) << 16; return x.f;
}
__device__ __forceinline__ u16 f2bf(float f) {
  union { float f; unsigned int u; } x; x.f = f;
  unsigned int lsb = (x.u >> 16) & 1u;
  return (u16)((x.u + 0x7fffu + lsb) >> 16);
}
// exact-GELU via A&S 7.1.26 erf (max abs err 1.5e-7), branchless
__device__ __forceinline__ float gelu_f(float x) {
  float z = fabsf(x) * 0.70710678118654752f;
  float t = __builtin_amdgcn_rcpf(1.f + 0.3275911f * z);
  float p = ((((1.061405429f * t - 1.453152027f) * t + 1.421413741f) * t
              - 0.284496736f) * t + 0.254829592f) * t;
  float e = __expf(-z * z);
  float erfv = copysignf(1.f - p * e, x);
  return 0.5f * x * (1.f + erfv);
}

// ---------------------------------------------------------------------------
// General GEMM (m97 structure, BK=64, mt-major tile order for XCD A-locality).
// MODE 0: A=A0. MODE 2: N-switch (nt0<SEL -> A0 else A1). SPLITK=1: atomicAdd.
// ---------------------------------------------------------------------------
template<int MODE, int SPLITK>
__launch_bounds__(256, 2)
__global__ void gemm_abt(const u16* __restrict__ A0, const u16* __restrict__ A1,
                         int SEL, int lda,
                         const u16* __restrict__ Bt,
                         u16* __restrict__ Cb, float* __restrict__ Cf,
                         int M, int N, int K,
                         long sAb, long sBb, long sCb)
{
  __shared__ __align__(16) u16 As[2 * 128 * 32];
  __shared__ __align__(16) u16 Bs[2 * 128 * 32];

  const int mtiles = M >> 7;
  const int tile = blockIdx.x;
  const int mt0 = (tile % mtiles) << 7;   // mt-major: same-A tiles same XCD
  const int nt0 = (tile / mtiles) << 7;
  const int kchunk = K / (int)gridDim.y;
  const int k0beg = blockIdx.y * kchunk;
  const int k0end = k0beg + kchunk;
  const int bz = blockIdx.z;
  A0 += (long)bz * sAb;  A1 += (long)bz * sAb;  Bt += (long)bz * sBb;

  const u16* Abase = (MODE == 2 && nt0 >= SEL) ? A1 : A0;

  const int tid  = threadIdx.x;
  const int wave = tid >> 6, lane = tid & 63;
  const int srow = lane >> 2;
  const int gq   = (lane & 3) ^ (srow & 3);
  const int frow = lane & 15;
  const int fq   = lane >> 4;
  const int fqx  = (fq ^ (frow & 3)) * 8;

  f32x4 zero = {0.f, 0.f, 0.f, 0.f};
  f32x4 acc[4][4];
#pragma unroll
  for (int i = 0; i < 4; i++)
#pragma unroll
    for (int j = 0; j < 4; j++) acc[i][j] = zero;

  const int wm = (wave & 1) * 64, wn = (wave >> 1) * 64;

  for (int k0 = k0beg; k0 < k0end; k0 += 64) {
    __syncthreads();
#pragma unroll
    for (int h = 0; h < 2; h++) {
#pragma unroll
      for (int i = 0; i < 2; i++) {
        const int chunk = i * 4 + wave;
        GLDS(&As[h * 4096 + chunk * 512],
             Abase + (long)(mt0 + chunk * 16 + srow) * lda + (k0 + h * 32 + gq * 8));
        GLDS(&Bs[h * 4096 + chunk * 512],
             Bt + (long)(nt0 + chunk * 16 + srow) * K + (k0 + h * 32 + gq * 8));
      }
    }
    __syncthreads();
#pragma unroll
    for (int h = 0; h < 2; h++) {
      short8 af[4], bf[4];
#pragma unroll
      for (int t = 0; t < 4; t++)
        af[t] = *(const short8*)&As[h * 4096 + (wm + t * 16 + frow) * 32 + fqx];
#pragma unroll
      for (int t = 0; t < 4; t++)
        bf[t] = *(const short8*)&Bs[h * 4096 + (wn + t * 16 + frow) * 32 + fqx];
#pragma unroll
      for (int mt = 0; mt < 4; mt++)
#pragma unroll
        for (int nt = 0; nt < 4; nt++)
          acc[mt][nt] = __builtin_amdgcn_mfma_f32_16x16x32_bf16(af[mt], bf[nt], acc[mt][nt], 0, 0, 0);
    }
  }

  if (SPLITK) {
    float* Cp = Cf + (long)bz * sCb;
#pragma unroll
    for (int mt = 0; mt < 4; mt++)
#pragma unroll
      for (int r = 0; r < 4; r++) {
        const int row = mt0 + wm + mt * 16 + fq * 4 + r;
#pragma unroll
        for (int nt = 0; nt < 4; nt++)
          atomicAdd(&Cp[(long)row * N + nt0 + wn + nt * 16 + frow], acc[mt][nt][r]);
      }
  } else {
    u16* Cp = Cb + (long)bz * sCb;
#pragma unroll
    for (int mt = 0; mt < 4; mt++)
#pragma unroll
      for (int r = 0; r < 4; r++) {
        const int row = mt0 + wm + mt * 16 + fq * 4 + r;
#pragma unroll
        for (int nt = 0; nt < 4; nt++)
          Cp[(long)row * N + nt0 + wn + nt * 16 + frow] = f2bf(acc[mt][nt][r]);
      }
  }
}

// ---------------------------------------------------------------------------
// GEMM (M-tile 64, N=256 full-width) + fused LayerNorm epilogue -> bf16 out.
// Used for: message = LN1(v @ Mt^T). A: rows at lda stride; B: 256x256.
// ---------------------------------------------------------------------------
__launch_bounds__(256, 2)
__global__ void gemm_ln(const u16* __restrict__ A, long sAb, int lda,
                        const u16* __restrict__ Bt, long sBb,
                        const float* __restrict__ gamma, const float* __restrict__ beta,
                        u16* __restrict__ outb)
{
  __shared__ __align__(16) u16 As[2 * 64 * 32];    // 8 KB
  __shared__ __align__(16) u16 Bs[2 * 256 * 32];   // 32 KB
  __shared__ float red_s[64][4], red_q[64][4];

  const int gm0 = blockIdx.x * 64;
  const int z  = gm0 >> 13;      // / L_
  const int ml = gm0 & (L_ - 1);
  A  += (long)z * sAb + (long)ml * lda;
  Bt += (long)z * sBb;

  const int tid = threadIdx.x, wave = tid >> 6, lane = tid & 63;
  const int srow = lane >> 2, gq = (lane & 3) ^ (srow & 3);
  const int frow = lane & 15, fq = lane >> 4;
  const int fqx = (fq ^ (frow & 3)) * 8;
  const int wn = wave * 64;

  f32x4 zero = {0.f, 0.f, 0.f, 0.f};
  f32x4 acc[4][4];
#pragma unroll
  for (int i = 0; i < 4; i++)
#pragma unroll
    for (int j = 0; j < 4; j++) acc[i][j] = zero;

  for (int k0 = 0; k0 < 256; k0 += 64) {
    __syncthreads();
#pragma unroll
    for (int h = 0; h < 2; h++) {
      GLDS(&As[h * 2048 + wave * 512],
           A + (long)(wave * 16 + srow) * lda + (k0 + h * 32 + gq * 8));
#pragma unroll
      for (int i = 0; i < 4; i++) {
        const int chunk = i * 4 + wave;
        GLDS(&Bs[h * 8192 + chunk * 512],
             Bt + (long)(chunk * 16 + srow) * 256 + (k0 + h * 32 + gq * 8));
      }
    }
    __syncthreads();
#pragma unroll
    for (int h = 0; h < 2; h++) {
      short8 af[4], bf[4];
#pragma unroll
      for (int t = 0; t < 4; t++)
        af[t] = *(const short8*)&As[h * 2048 + (t * 16 + frow) * 32 + fqx];
#pragma unroll
      for (int t = 0; t < 4; t++)
        bf[t] = *(const short8*)&Bs[h * 8192 + (wn + t * 16 + frow) * 32 + fqx];
#pragma unroll
      for (int mt = 0; mt < 4; mt++)
#pragma unroll
        for (int nt = 0; nt < 4; nt++)
          acc[mt][nt] = __builtin_amdgcn_mfma_f32_16x16x32_bf16(af[mt], bf[nt], acc[mt][nt], 0, 0, 0);
    }
  }

  // LN epilogue: stats over all 256 cols of each of the 64 rows.
  float gv[4], bv[4];
#pragma unroll
  for (int nt = 0; nt < 4; nt++) {
    const int col = wn + nt * 16 + frow;
    gv[nt] = gamma[col]; bv[nt] = beta[col];
  }
#pragma unroll
  for (int mt = 0; mt < 4; mt++)
#pragma unroll
    for (int r = 0; r < 4; r++) {
      float s = 0.f, q = 0.f;
#pragma unroll
      for (int nt = 0; nt < 4; nt++) {
        float v = acc[mt][nt][r]; s += v; q += v * v;
      }
#pragma unroll
      for (int m = 1; m < 16; m <<= 1) {
        s += __shfl_xor(s, m, 16); q += __shfl_xor(q, m, 16);
      }
      if (frow == 0) {
        const int row = mt * 16 + fq * 4 + r;
        red_s[row][wave] = s; red_q[row][wave] = q;
      }
    }
  __syncthreads();
#pragma unroll
  for (int mt = 0; mt < 4; mt++)
#pragma unroll
    for (int r = 0; r < 4; r++) {
      const int row = mt * 16 + fq * 4 + r;
      float4 ss = *(const float4*)red_s[row];
      float4 qq = *(const float4*)red_q[row];
      const float s = ss.x + ss.y + ss.z + ss.w;
      const float q = qq.x + qq.y + qq.z + qq.w;
      const float mu = s * (1.f / 256.f);
      const float var = q * (1.f / 256.f) - mu * mu;
      const float rs = 1.f / sqrtf(var + EPS_);
      const long grow = gm0 + row;
#pragma unroll
      for (int nt = 0; nt < 4; nt++) {
        const int col = wn + nt * 16 + frow;
        outb[grow * 256 + col] = f2bf((acc[mt][nt][r] - mu) * rs * gv[nt] + bv[nt]);
      }
    }
}

// ---------------------------------------------------------------------------
// Fused FFN: out = source + LN2( gelu([srcB|message]@W1 + b1) @ W2 + b2 )
// Block = 64 M-rows x 256 N-cols. Loops 16 hidden slices of 128:
//   stage1: Hs = gelu(A@W1-slice + b1)  (4 waves x 64x32)  -> LDS (padded)
//   stage2: acc2 += Hs @ W2-slice       (4 waves x 64x64 out quadrants)
// hidden never touches HBM. LN2 + fp32 residual fused into epilogue.
// ---------------------------------------------------------------------------
__launch_bounds__(256, 2)
__global__ void ffn_fused(const u16* __restrict__ srcB, const u16* __restrict__ message,
                          const u16* __restrict__ W1T, const float* __restrict__ b1,
                          const u16* __restrict__ W2T, const float* __restrict__ b2,
                          const float* __restrict__ gamma2, const float* __restrict__ beta2,
                          const float* __restrict__ source, float* __restrict__ out)
{
  __shared__ __align__(16) u16 As[2 * 64 * 32];     // 8 KB
  __shared__ __align__(16) u16 Bs1[2 * 128 * 32];   // 16 KB
  __shared__ __align__(16) u16 Bs2[2 * 256 * 32];   // 32 KB
  __shared__ __align__(16) u16 Hs[64 * 136];        // 17 KB (pad +8: bank spread)
  __shared__ float red_s[64][4], red_q[64][4];      // 2 KB

  const int m0 = blockIdx.x * 64;
  const int tid = threadIdx.x, wave = tid >> 6, lane = tid & 63;
  const int srow = lane >> 2, gq = (lane & 3) ^ (srow & 3);
  const int frow = lane & 15, fq = lane >> 4;
  const int fqx = (fq ^ (frow & 3)) * 8;
  const int wn1 = wave * 32;   // stage1 Hs col strip
  const int wn2 = wave * 64;   // stage2 out col quadrant

  f32x4 zero = {0.f, 0.f, 0.f, 0.f};
  f32x4 acc2[4][4];
#pragma unroll
  for (int i = 0; i < 4; i++)
#pragma unroll
    for (int j = 0; j < 4; j++) acc2[i][j] = zero;

  for (int hs = 0; hs < 16; hs++) {
    f32x4 acc1[4][2];
#pragma unroll
    for (int i = 0; i < 4; i++) { acc1[i][0] = zero; acc1[i][1] = zero; }

    // ---- stage 1: Hs = gelu(A @ W1[:, hs*128..+128] + b1), K=512 ----
    for (int it = 0; it < 8; it++) {
      const int k0 = it * 64;
      const u16* Asrc = (k0 < 256) ? srcB : message;
      const int ka = k0 & 255;
      __syncthreads();
#pragma unroll
      for (int h = 0; h < 2; h++) {
        GLDS(&As[h * 2048 + wave * 512],
             Asrc + (long)(m0 + wave * 16 + srow) * 256 + (ka + h * 32 + gq * 8));
#pragma unroll
        for (int i = 0; i < 2; i++) {
          const int chunk = i * 4 + wave;
          GLDS(&Bs1[h * 4096 + chunk * 512],
               W1T + (long)(hs * 128 + chunk * 16 + srow) * 512 + (k0 + h * 32 + gq * 8));
        }
      }
      __syncthreads();
#pragma unroll
      for (int h = 0; h < 2; h++) {
        short8 af[4], bf[2];
#pragma unroll
        for (int t = 0; t < 4; t++)
          af[t] = *(const short8*)&As[h * 2048 + (t * 16 + frow) * 32 + fqx];
#pragma unroll
        for (int t = 0; t < 2; t++)
          bf[t] = *(const short8*)&Bs1[h * 4096 + (wn1 + t * 16 + frow) * 32 + fqx];
#pragma unroll
        for (int mt = 0; mt < 4; mt++)
#pragma unroll
          for (int nt = 0; nt < 2; nt++)
            acc1[mt][nt] = __builtin_amdgcn_mfma_f32_16x16x32_bf16(af[mt], bf[nt], acc1[mt][nt], 0, 0, 0);
      }
    }
    // bias + gelu -> Hs (bf16, padded rows)
    float b1v[2];
#pragma unroll
    for (int nt = 0; nt < 2; nt++)
      b1v[nt] = b1[hs * 128 + wn1 + nt * 16 + frow];
#pragma unroll
    for (int mt = 0; mt < 4; mt++)
#pragma unroll
      for (int nt = 0; nt < 2; nt++)
#pragma unroll
        for (int r = 0; r < 4; r++) {
          const int row = mt * 16 + fq * 4 + r;
          Hs[row * 136 + wn1 + nt * 16 + frow] = f2bf(gelu_f(acc1[mt][nt][r] + b1v[nt]));
        }

    // ---- stage 2: acc2 += Hs @ W2[hs-slice, :], K=128 (2 x BK64) ----
    for (int it2 = 0; it2 < 2; it2++) {
      __syncthreads();   // orders Hs writes (it2=0) / prev Bs2 reads before DMA
#pragma unroll
      for (int h = 0; h < 2; h++)
#pragma unroll
        for (int i = 0; i < 4; i++) {
          const int chunk = i * 4 + wave;
          GLDS(&Bs2[h * 8192 + chunk * 512],
               W2T + (long)(chunk * 16 + srow) * 2048
                   + (hs * 128 + it2 * 64 + h * 32 + gq * 8));
        }
      __syncthreads();
#pragma unroll
      for (int kk = 0; kk < 2; kk++) {
        short8 a2[4], b2f[4];
#pragma unroll
        for (int t = 0; t < 4; t++)
          a2[t] = *(const short8*)&Hs[(t * 16 + frow) * 136 + it2 * 64 + kk * 32 + fq * 8];
#pragma unroll
        for (int t = 0; t < 4; t++)
          b2f[t] = *(const short8*)&Bs2[kk * 8192 + (wn2 + t * 16 + frow) * 32 + fqx];
#pragma unroll
        for (int mt = 0; mt < 4; mt++)
#pragma unroll
          for (int nt = 0; nt < 4; nt++)
            acc2[mt][nt] = __builtin_amdgcn_mfma_f32_16x16x32_bf16(a2[mt], b2f[nt], acc2[mt][nt], 0, 0, 0);
      }
    }
  }

  // ---- epilogue: + b2, LN2, + source residual -> fp32 out ----
  float b2v[4], gv[4], bv[4];
#pragma unroll
  for (int nt = 0; nt < 4; nt++) {
    const int col = wn2 + nt * 16 + frow;
    b2v[nt] = b2[col]; gv[nt] = gamma2[col]; bv[nt] = beta2[col];
  }
#pragma unroll
  for (int mt = 0; mt < 4; mt++)
#pragma unroll
    for (int r = 0; r < 4; r++) {
      float s = 0.f, q = 0.f;
#pragma unroll
      for (int nt = 0; nt < 4; nt++) {
        float v = acc2[mt][nt][r] + b2v[nt];
        acc2[mt][nt][r] = v; s += v; q += v * v;
      }
#pragma unroll
      for (int m = 1; m < 16; m <<= 1) {
        s += __shfl_xor(s, m, 16); q += __shfl_xor(q, m, 16);
      }
      if (frow == 0) {
        const int row = mt * 16 + fq * 4 + r;
        red_s[row][wave] = s; red_q[row][wave] = q;
      }
    }
  __syncthreads();
#pragma unroll
  for (int mt = 0; mt < 4; mt++)
#pragma unroll
    for (int r = 0; r < 4; r++) {
      const int row = mt * 16 + fq * 4 + r;
      float4 ss = *(const float4*)red_s[row];
      float4 qq = *(const float4*)red_q[row];
      const float s = ss.x + ss.y + ss.z + ss.w;
      const float q = qq.x + qq.y + qq.z + qq.w;
      const float mu = s * (1.f / 256.f);
      const float var = q * (1.f / 256.f) - mu * mu;
      const float rs = 1.f / sqrtf(var + EPS_);
      const long grow = m0 + row;
#pragma unroll
      for (int nt = 0; nt < 4; nt++) {
        const int col = wn2 + nt * 16 + frow;
        out[grow * 256 + col] = (acc2[mt][nt][r] - mu) * rs * gv[nt] + bv[nt]
                                + source[grow * 256 + col];
      }
    }
}

// ---------------------------------------------------------------------------
__global__ void transpose2d(const u16* __restrict__ in, u16* __restrict__ out,
                            int R, int Cc, int ldi, long sIb, long sOb)
{
  __shared__ u16 t[32][33];
  const int bx = blockIdx.x * 32, by = blockIdx.y * 32;
  in  += (long)blockIdx.z * sIb;
  out += (long)blockIdx.z * sOb;
  const int tx = threadIdx.x, ty = threadIdx.y;
#pragma unroll
  for (int i = ty; i < 32; i += 8)
    t[i][tx] = in[(long)(by + i) * ldi + bx + tx];
  __syncthreads();
#pragma unroll
  for (int i = ty; i < 32; i += 8)
    out[(long)(bx + i) * R + by + tx] = t[tx][i];
}

__global__ void transpose_f2b(const float* __restrict__ in, u16* __restrict__ out,
                              int R, int Cc)
{
  __shared__ u16 t[32][33];
  const int bx = blockIdx.x * 32, by = blockIdx.y * 32;
  const int tx = threadIdx.x, ty = threadIdx.y;
#pragma unroll
  for (int i = ty; i < 32; i += 8)
    t[i][tx] = f2bf(in[(long)(by + i) * Cc + bx + tx]);
  __syncthreads();
#pragma unroll
  for (int i = ty; i < 32; i += 8)
    out[(long)(bx + i) * R + by + tx] = t[tx][i];
}

__global__ void pack_w256(const float* __restrict__ w0, const float* __restrict__ w1,
                          const float* __restrict__ w2, const float* __restrict__ w3,
                          u16* __restrict__ qkvT, u16* __restrict__ wlT)
{
  __shared__ u16 t[32][33];
  const int z = blockIdx.z;
  const float* in = (z == 0) ? w0 : (z == 1) ? w1 : (z == 2) ? w2 : w3;
  u16* out = (z < 3) ? (qkvT + (long)z * C_ * C_) : wlT;
  const int bx = blockIdx.x * 32, by = blockIdx.y * 32;
  const int tx = threadIdx.x, ty = threadIdx.y;
#pragma unroll
  for (int i = ty; i < 32; i += 8)
    t[i][tx] = f2bf(in[(long)(by + i) * C_ + bx + tx]);
  __syncthreads();
#pragma unroll
  for (int i = ty; i < 32; i += 8)
    out[(long)(bx + i) * C_ + by + tx] = t[tx][i];
}

__global__ void cast2_f2b(const float* __restrict__ in0, const float* __restrict__ in1,
                          u16* __restrict__ out0, u16* __restrict__ out1)
{
  const float* in = blockIdx.y ? in1 : in0;
  u16* out = blockIdx.y ? out1 : out0;
  int i = (blockIdx.x * 256 + threadIdx.x) * 4;
  float4 v = *(const float4*)(in + i);
  ushort4 o; o.x = f2bf(v.x); o.y = f2bf(v.y); o.z = f2bf(v.z); o.w = f2bf(v.w);
  *(ushort4*)(out + i) = o;
}

__global__ void softmax_rows(u16* __restrict__ data, int rowlen)
{
  const long base = (long)blockIdx.x * rowlen;
  const int tid = threadIdx.x, wave = tid >> 6, lane = tid & 63;
  __shared__ float red[4];

  float m = -3.4e38f;
  for (int i = tid; i < rowlen; i += 256) m = fmaxf(m, bf2f(data[base + i]));
#pragma unroll
  for (int off = 32; off; off >>= 1) m = fmaxf(m, __shfl_xor(m, off, 64));
  if (lane == 0) red[wave] = m;
  __syncthreads();
  m = fmaxf(fmaxf(red[0], red[1]), fmaxf(red[2], red[3]));
  __syncthreads();

  float s = 0.f;
  for (int i = tid; i < rowlen; i += 256) s += expf(bf2f(data[base + i]) - m);
#pragma unroll
  for (int off = 32; off; off >>= 1) s += __shfl_xor(s, off, 64);
  if (lane == 0) red[wave] = s;
  __syncthreads();
  const float inv = 1.f / (red[0] + red[1] + red[2] + red[3]);
  for (int i = tid; i < rowlen; i += 256)
    data[base + i] = f2bf(expf(bf2f(data[base + i]) - m) * inv);
}

__global__ void zero_f32(float* __restrict__ p, int n) {
  int i = blockIdx.x * 256 + threadIdx.x;
  if (i < n) p[i] = 0.f;
}
__global__ void f32_to_bf16_k(const float* __restrict__ in, u16* __restrict__ out, int n) {
  int i = blockIdx.x * 256 + threadIdx.x;
  if (i < n) out[i] = f2bf(in[i]);
}

// ---------------------------------------------------------------------------
extern "C" void kernel_launch(void* const* d_in, const int* in_sizes, int n_in,
                              void* d_out, int out_size, void* d_ws, size_t ws_size,
                              hipStream_t stream)
{
  const float* source = (const float*)d_in[0];
  const float* target = (const float*)d_in[1];
  const float* Wq     = (const float*)d_in[2];
  const float* Wk     = (const float*)d_in[3];
  const float* Wv     = (const float*)d_in[4];
  const float* Wl     = (const float*)d_in[5];
  const float* gamma1 = (const float*)d_in[6];
  const float* beta1  = (const float*)d_in[7];
  const float* W1     = (const float*)d_in[8];
  const float* b1     = (const float*)d_in[9];
  const float* W2     = (const float*)d_in[10];
  const float* b2     = (const float*)d_in[11];
  const float* gamma2 = (const float*)d_in[12];
  const float* beta2  = (const float*)d_in[13];
  (void)in_sizes; (void)n_in; (void)out_size; (void)ws_size;

  char* ws = (char*)d_ws;
  size_t off = 0;
  auto take = [&](size_t bytes) -> char* {
    char* p = ws + off; off += (bytes + 255) & ~(size_t)255; return p;
  };
  u16*   WqkvT = (u16*)take((size_t)768 * C_ * 2);
  u16*   WlT   = (u16*)take((size_t)C_ * C_ * 2);
  u16*   W1T   = (u16*)take((size_t)FFN_ * KCAT_ * 2);
  u16*   W2T   = (u16*)take((size_t)C_ * FFN_ * 2);
  float* ctxTf = (float*)take((size_t)B_ * C_ * C_ * 4);
  u16*   ctxTb = (u16*)take((size_t)B_ * C_ * C_ * 2);
  u16*   Mtb   = (u16*)take((size_t)B_ * C_ * C_ * 2);
  u16*   srcB  = (u16*)take((size_t)BLC_ * 2);
  u16*   tgtB  = (u16*)take((size_t)BLC_ * 2);
  u16*   QKV   = (u16*)take((size_t)BL_ * 768 * 2);
  u16*   qT    = (u16*)take((size_t)BLC_ * 2);
  u16*   kT    = (u16*)take((size_t)BLC_ * 2);
  u16*   msg   = (u16*)take((size_t)BLC_ * 2);

  dim3 tb(32, 8);
  cast2_f2b<<<dim3(BLC_ / 1024, 2), 256, 0, stream>>>(source, target, srcB, tgtB);
  pack_w256<<<dim3(8, 8, 4), tb, 0, stream>>>(Wq, Wk, Wv, Wl, WqkvT, WlT);
  transpose_f2b<<<dim3(FFN_/32, KCAT_/32), tb, 0, stream>>>(W1, W1T, KCAT_, FFN_);
  transpose_f2b<<<dim3(C_/32,  FFN_/32), tb, 0, stream>>>(W2, W2T, FFN_, C_);
  zero_f32<<<(B_*C_*C_)/256, 256, 0, stream>>>(ctxTf, B_*C_*C_);

  // Fused QKV: [q|k|v] = [src|tgt|tgt] @ [Wq|Wk|Wv]
  gemm_abt<2,0><<<dim3((BL_/128)*(768/128)), 256, 0, stream>>>(
      srcB, tgtB, 256, C_, WqkvT, QKV, nullptr, BL_, 768, C_, 0, 0, 0);

  transpose2d<<<dim3(C_/32, L_/32, B_), tb, 0, stream>>>(QKV,       qT, L_, C_, 768, (long)L_*768, (long)L_*C_);
  transpose2d<<<dim3(C_/32, L_/32, B_), tb, 0, stream>>>(QKV + 256, kT, L_, C_, 768, (long)L_*768, (long)L_*C_);
  softmax_rows<<<B_*C_, 256, 0, stream>>>(kT, L_);

  // ctxT[e,d] = sum_n ksm[n,e] q[n,d]  (split-K over tokens)
  gemm_abt<0,1><<<dim3(4, 16, B_), 256, 0, stream>>>(
      kT, kT, 0, L_, qT, nullptr, ctxTf, C_, C_, L_,
      (long)C_*L_, (long)C_*L_, (long)C_*C_);
  f32_to_bf16_k<<<(B_*C_*C_)/256, 256, 0, stream>>>(ctxTf, ctxTb, B_*C_*C_);

  // Mt[c,e] = sum_d WlT[c,d] * ctxT[e,d]
  gemm_abt<0,0><<<dim3(4, 1, B_), 256, 0, stream>>>(
      WlT, WlT, 0, C_, ctxTb, Mtb, nullptr, C_, C_, C_,
      0, (long)C_*C_, (long)C_*C_);

  // message = LN1( v @ Mt^T )   (v strided inside QKV, lda=768)
  gemm_ln<<<BL_/64, 256, 0, stream>>>(
      QKV + 512, (long)L_*768, 768, Mtb, (long)C_*C_, gamma1, beta1, msg);

  // out = source + LN2( gelu([src|msg]@W1+b1) @ W2 + b2 )
  ffn_fused<<<BL_/64, 256, 0, stream>>>(
      srcB, msg, W1T, b1, W2T, b2, gamma2, beta2, source, (float*)d_out);
}

// Round 5
// 419.346 us; speedup vs baseline: 1.0719x; 1.0719x over previous
//
#include <hip/hip_runtime.h>
#include <hip/hip_bf16.h>

typedef unsigned short u16;
typedef __attribute__((ext_vector_type(8))) short short8;   // 8 x bf16 = 4 VGPRs
typedef __attribute__((ext_vector_type(4))) float f32x4;

#define B_    4
#define L_    8192
#define C_    256
#define BL_   (B_*L_)
#define BLC_  (BL_*C_)
#define FFN_  2048
#define EPS_  1e-5f

#define GLDS(dst, src) __builtin_amdgcn_global_load_lds( \
    (const __attribute__((address_space(1))) unsigned int*)(src), \
    (__attribute__((address_space(3))) unsigned int*)(dst), 16, 0, 0)

__device__ __forceinline__ float bf2f(u16 v) {
  union { unsigned int u; float f; } x; x.u = ((unsigned int)v) << 16; return x.f;
}
__device__ __forceinline__ u16 f2bf(float f) {
  union { float f; unsigned int u; } x; x.f = f;
  unsigned int lsb = (x.u >> 16) & 1u;
  return (u16)((x.u + 0x7fffu + lsb) >> 16);
}
// exact-GELU via A&S 7.1.26 erf (max abs err 1.5e-7), branchless
__device__ __forceinline__ float gelu_f(float x) {
  float z = fabsf(x) * 0.70710678118654752f;
  float t = __builtin_amdgcn_rcpf(1.f + 0.3275911f * z);
  float p = ((((1.061405429f * t - 1.453152027f) * t + 1.421413741f) * t
              - 0.284496736f) * t + 0.254829592f) * t;
  float e = __expf(-z * z);
  float erfv = copysignf(1.f - p * e, x);
  return 0.5f * x * (1.f + erfv);
}

// ---------------------------------------------------------------------------
// General GEMM: C[m,n] = act( sum_k A[m,k]*Bt[n,k] + bias[n] )
// m97 structure, 128x128 tile, BK=64, DMA quad-XOR swizzle, mt-major tiles.
// MODE 0: A=A0. MODE 1: K-concat at SEL. MODE 2: N-switch at SEL (QKV).
// ACT 1: gelu. SPLITK 1: fp32 atomicAdd into Cf.
// ---------------------------------------------------------------------------
template<int MODE, int ACT, int SPLITK>
__launch_bounds__(256, 2)
__global__ void gemm_abt(const u16* __restrict__ A0, const u16* __restrict__ A1,
                         int SEL, int lda,
                         const u16* __restrict__ Bt,
                         const float* __restrict__ bias,
                         u16* __restrict__ Cb, float* __restrict__ Cf,
                         int M, int N, int K,
                         long sAb, long sBb, long sCb)
{
  __shared__ __align__(16) u16 As[2 * 128 * 32];
  __shared__ __align__(16) u16 Bs[2 * 128 * 32];

  const int mtiles = M >> 7;
  const int tile = blockIdx.x;
  const int mt0 = (tile % mtiles) << 7;
  const int nt0 = (tile / mtiles) << 7;
  const int kchunk = K / (int)gridDim.y;
  const int k0beg = blockIdx.y * kchunk;
  const int k0end = k0beg + kchunk;
  const int bz = blockIdx.z;
  A0 += (long)bz * sAb;  A1 += (long)bz * sAb;  Bt += (long)bz * sBb;

  const u16* Abase = (MODE == 2 && nt0 >= SEL) ? A1 : A0;

  const int tid  = threadIdx.x;
  const int wave = tid >> 6, lane = tid & 63;
  const int srow = lane >> 2;
  const int gq   = (lane & 3) ^ (srow & 3);
  const int frow = lane & 15;
  const int fq   = lane >> 4;
  const int fqx  = (fq ^ (frow & 3)) * 8;

  f32x4 zero = {0.f, 0.f, 0.f, 0.f};
  f32x4 acc[4][4];
#pragma unroll
  for (int i = 0; i < 4; i++)
#pragma unroll
    for (int j = 0; j < 4; j++) acc[i][j] = zero;

  const int wm = (wave & 1) * 64, wn = (wave >> 1) * 64;

  for (int k0 = k0beg; k0 < k0end; k0 += 64) {
    __syncthreads();
    const u16* Asrc;
    int ka;
    if (MODE == 1) {
      const bool lo = (k0 < SEL);
      Asrc = lo ? A0 : A1;
      ka = lo ? k0 : (k0 - SEL);
    } else { Asrc = Abase; ka = k0; }
#pragma unroll
    for (int h = 0; h < 2; h++) {
#pragma unroll
      for (int i = 0; i < 2; i++) {
        const int chunk = i * 4 + wave;
        GLDS(&As[h * 4096 + chunk * 512],
             Asrc + (long)(mt0 + chunk * 16 + srow) * lda + (ka + h * 32 + gq * 8));
        GLDS(&Bs[h * 4096 + chunk * 512],
             Bt + (long)(nt0 + chunk * 16 + srow) * K + (k0 + h * 32 + gq * 8));
      }
    }
    __syncthreads();
#pragma unroll
    for (int h = 0; h < 2; h++) {
      short8 af[4], bf[4];
#pragma unroll
      for (int t = 0; t < 4; t++)
        af[t] = *(const short8*)&As[h * 4096 + (wm + t * 16 + frow) * 32 + fqx];
#pragma unroll
      for (int t = 0; t < 4; t++)
        bf[t] = *(const short8*)&Bs[h * 4096 + (wn + t * 16 + frow) * 32 + fqx];
#pragma unroll
      for (int mt = 0; mt < 4; mt++)
#pragma unroll
        for (int nt = 0; nt < 4; nt++)
          acc[mt][nt] = __builtin_amdgcn_mfma_f32_16x16x32_bf16(af[mt], bf[nt], acc[mt][nt], 0, 0, 0);
    }
  }

  if (SPLITK) {
    float* Cp = Cf + (long)bz * sCb;
#pragma unroll
    for (int mt = 0; mt < 4; mt++)
#pragma unroll
      for (int r = 0; r < 4; r++) {
        const int row = mt0 + wm + mt * 16 + fq * 4 + r;
#pragma unroll
        for (int nt = 0; nt < 4; nt++)
          atomicAdd(&Cp[(long)row * N + nt0 + wn + nt * 16 + frow], acc[mt][nt][r]);
      }
  } else {
    u16* Cp = Cb + (long)bz * sCb;
    float bv[4];
#pragma unroll
    for (int nt = 0; nt < 4; nt++)
      bv[nt] = bias ? bias[nt0 + wn + nt * 16 + frow] : 0.f;
#pragma unroll
    for (int mt = 0; mt < 4; mt++)
#pragma unroll
      for (int r = 0; r < 4; r++) {
        const int row = mt0 + wm + mt * 16 + fq * 4 + r;
#pragma unroll
        for (int nt = 0; nt < 4; nt++) {
          float v = acc[mt][nt][r] + bv[nt];
          if (ACT == 1) v = gelu_f(v);
          Cp[(long)row * N + nt0 + wn + nt * 16 + frow] = f2bf(v);
        }
      }
  }
}

// ---------------------------------------------------------------------------
// GEMM (M-tile 64, full N=256) + fused LayerNorm epilogue.
// CVTB=1: B operand is fp32 (converted during LDS staging).
// OUTF=0: out bf16 (message=LN1). OUTF=1: +bias, LN2, +fp32 src residual,
// fp32 out (final FFN2).  z = gm0 >> zshift selects batch for A/B strides.
// ---------------------------------------------------------------------------
template<int CVTB, int OUTF>
__launch_bounds__(256, 3)
__global__ void gemm_ln(const u16* __restrict__ A, long sAb, int lda, int K,
                        const void* __restrict__ Btv, long sBb, int zshift,
                        const float* __restrict__ bias,
                        const float* __restrict__ gamma, const float* __restrict__ beta,
                        const float* __restrict__ src, void* __restrict__ outv,
                        long Moff)
{
  __shared__ __align__(16) u16 As[2 * 64 * 32];    // 8 KB
  __shared__ __align__(16) u16 Bs[2 * 256 * 32];   // 32 KB
  __shared__ float red_s[64][4], red_q[64][4];

  const int gm0 = blockIdx.x * 64;
  const int z = gm0 >> zshift;
  const int ml = gm0 - (z << zshift);
  A += (long)z * sAb + (long)ml * lda;
  const float* Bf = (const float*)Btv + (CVTB ? (long)z * sBb : 0);
  const u16*   Bb = (const u16*)Btv   + (CVTB ? 0 : (long)z * sBb);

  const int tid = threadIdx.x, wave = tid >> 6, lane = tid & 63;
  const int srow = lane >> 2, gq = (lane & 3) ^ (srow & 3);
  const int frow = lane & 15, fq = lane >> 4;
  const int fqx = (fq ^ (frow & 3)) * 8;
  const int wn = wave * 64;

  f32x4 zero = {0.f, 0.f, 0.f, 0.f};
  f32x4 acc[4][4];
#pragma unroll
  for (int i = 0; i < 4; i++)
#pragma unroll
    for (int j = 0; j < 4; j++) acc[i][j] = zero;

  for (int k0 = 0; k0 < K; k0 += 64) {
    __syncthreads();
#pragma unroll
    for (int h = 0; h < 2; h++) {
      GLDS(&As[h * 2048 + wave * 512],
           A + (long)(wave * 16 + srow) * lda + (k0 + h * 32 + gq * 8));
#pragma unroll
      for (int i = 0; i < 4; i++) {
        const int chunk = i * 4 + wave;
        if (CVTB) {
          const float* bp = Bf + (long)(chunk * 16 + srow) * K + (k0 + h * 32 + gq * 8);
          float4 p0 = *(const float4*)bp;
          float4 p1 = *(const float4*)(bp + 4);
          short8 w;
          w[0] = (short)f2bf(p0.x); w[1] = (short)f2bf(p0.y);
          w[2] = (short)f2bf(p0.z); w[3] = (short)f2bf(p0.w);
          w[4] = (short)f2bf(p1.x); w[5] = (short)f2bf(p1.y);
          w[6] = (short)f2bf(p1.z); w[7] = (short)f2bf(p1.w);
          *(short8*)&Bs[h * 8192 + chunk * 512 + srow * 32 + (lane & 3) * 8] = w;
        } else {
          GLDS(&Bs[h * 8192 + chunk * 512],
               Bb + (long)(chunk * 16 + srow) * K + (k0 + h * 32 + gq * 8));
        }
      }
    }
    __syncthreads();
#pragma unroll
    for (int h = 0; h < 2; h++) {
      short8 af[4], bf[4];
#pragma unroll
      for (int t = 0; t < 4; t++)
        af[t] = *(const short8*)&As[h * 2048 + (t * 16 + frow) * 32 + fqx];
#pragma unroll
      for (int t = 0; t < 4; t++)
        bf[t] = *(const short8*)&Bs[h * 8192 + (wn + t * 16 + frow) * 32 + fqx];
#pragma unroll
      for (int mt = 0; mt < 4; mt++)
#pragma unroll
        for (int nt = 0; nt < 4; nt++)
          acc[mt][nt] = __builtin_amdgcn_mfma_f32_16x16x32_bf16(af[mt], bf[nt], acc[mt][nt], 0, 0, 0);
    }
  }

  // LN epilogue over the 256 cols of each of the 64 rows.
  float gv[4], bv[4], b2v[4];
#pragma unroll
  for (int nt = 0; nt < 4; nt++) {
    const int col = wn + nt * 16 + frow;
    gv[nt] = gamma[col]; bv[nt] = beta[col];
    b2v[nt] = OUTF ? bias[col] : 0.f;
  }
#pragma unroll
  for (int mt = 0; mt < 4; mt++)
#pragma unroll
    for (int r = 0; r < 4; r++) {
      float s = 0.f, q = 0.f;
#pragma unroll
      for (int nt = 0; nt < 4; nt++) {
        float v = acc[mt][nt][r] + b2v[nt];
        acc[mt][nt][r] = v; s += v; q += v * v;
      }
#pragma unroll
      for (int m = 1; m < 16; m <<= 1) {
        s += __shfl_xor(s, m, 16); q += __shfl_xor(q, m, 16);
      }
      if (frow == 0) {
        const int row = mt * 16 + fq * 4 + r;
        red_s[row][wave] = s; red_q[row][wave] = q;
      }
    }
  __syncthreads();
#pragma unroll
  for (int mt = 0; mt < 4; mt++)
#pragma unroll
    for (int r = 0; r < 4; r++) {
      const int row = mt * 16 + fq * 4 + r;
      float4 ss = *(const float4*)red_s[row];
      float4 qq = *(const float4*)red_q[row];
      const float s = ss.x + ss.y + ss.z + ss.w;
      const float q = qq.x + qq.y + qq.z + qq.w;
      const float mu = s * (1.f / 256.f);
      const float var = q * (1.f / 256.f) - mu * mu;
      const float rs = 1.f / sqrtf(var + EPS_);
      const long grow = Moff + gm0 + row;
#pragma unroll
      for (int nt = 0; nt < 4; nt++) {
        const int col = wn + nt * 16 + frow;
        const float o = (acc[mt][nt][r] - mu) * rs * gv[nt] + bv[nt];
        if (OUTF)
          ((float*)outv)[grow * 256 + col] = o + src[grow * 256 + col];
        else
          ((u16*)outv)[grow * 256 + col] = f2bf(o);
      }
    }
}

// ---------------------------------------------------------------------------
// All weight packing in one launch. 1792 blocks of (32,8):
//  [0,256):   4x 256x256: Wq straight-cast; Wl,Wk,Wv transposed
//  [256,1280): W1 (512x2048) -> W1T (2048x512)
//  [1280,1792): W2 (2048x256) -> W2T (256x2048)
// ---------------------------------------------------------------------------
__global__ void weightpack(const float* __restrict__ Wq, const float* __restrict__ Wk,
                           const float* __restrict__ Wv, const float* __restrict__ Wl,
                           const float* __restrict__ W1, const float* __restrict__ W2,
                           u16* __restrict__ WqC, u16* __restrict__ WlT,
                           u16* __restrict__ WqkvT, u16* __restrict__ W1T,
                           u16* __restrict__ W2T)
{
  __shared__ u16 t[32][33];
  const int bid = blockIdx.x, tx = threadIdx.x, ty = threadIdx.y;
  const float* in; u16* out; int Cc, R, bx, by;
  if (bid < 256) {
    const int w = bid >> 6, tt = bid & 63;
    bx = (tt & 7) * 32; by = (tt >> 3) * 32; Cc = 256; R = 256;
    if (w == 0) {
#pragma unroll
      for (int i = ty; i < 32; i += 8)
        WqC[(long)(by + i) * 256 + bx + tx] = f2bf(Wq[(long)(by + i) * 256 + bx + tx]);
      return;
    }
    in  = (w == 1) ? Wl : (w == 2) ? Wk : Wv;
    out = (w == 1) ? WlT : (w == 2) ? (WqkvT + 65536) : (WqkvT + 131072);
  } else if (bid < 1280) {
    const int l = bid - 256; bx = (l & 63) * 32; by = (l >> 6) * 32;
    in = W1; out = W1T; Cc = 2048; R = 512;
  } else {
    const int l = bid - 1280; bx = (l & 7) * 32; by = (l >> 3) * 32;
    in = W2; out = W2T; Cc = 256; R = 2048;
  }
#pragma unroll
  for (int i = ty; i < 32; i += 8)
    t[i][tx] = f2bf(in[(long)(by + i) * Cc + bx + tx]);
  __syncthreads();
#pragma unroll
  for (int i = ty; i < 32; i += 8)
    out[(long)(bx + i) * R + by + tx] = t[tx][i];
}

// cast source/target fp32->bf16 (grid.y selects) + zero Mtf (tail blocks)
__global__ void castzero(const float* __restrict__ src, const float* __restrict__ tgt,
                         u16* __restrict__ srcB, u16* __restrict__ tgtB,
                         float* __restrict__ Mtf)
{
  const int x = blockIdx.x;
  if (x < BLC_ / 1024) {
    const float* in = blockIdx.y ? tgt : src;
    u16* out = blockIdx.y ? tgtB : srcB;
    const int i = (x * 256 + threadIdx.x) * 4;
    float4 v = *(const float4*)(in + i);
    ushort4 o; o.x = f2bf(v.x); o.y = f2bf(v.y); o.z = f2bf(v.z); o.w = f2bf(v.w);
    *(ushort4*)(out + i) = o;
  } else if (blockIdx.y == 0) {
    const int i = ((x - BLC_ / 1024) * 256 + threadIdx.x) * 4;
    float4 zv = {0.f, 0.f, 0.f, 0.f};
    *(float4*)(Mtf + i) = zv;
  }
}

// ql,k slices of QKV (B,L,768) -> (B,C,L). z<4: ql batches; z>=4: k batches.
__global__ void transQK(const u16* __restrict__ QKV,
                        u16* __restrict__ qlT, u16* __restrict__ kT)
{
  __shared__ u16 t[32][33];
  const int z = blockIdx.z, zb = z & 3;
  const u16* in = QKV + (long)zb * L_ * 768 + (z < 4 ? 0 : 256);
  u16* out = (z < 4 ? qlT : kT) + (long)zb * L_ * C_;
  const int bx = blockIdx.x * 32, by = blockIdx.y * 32;
  const int tx = threadIdx.x, ty = threadIdx.y;
#pragma unroll
  for (int i = ty; i < 32; i += 8)
    t[i][tx] = in[(long)(by + i) * 768 + bx + tx];
  __syncthreads();
#pragma unroll
  for (int i = ty; i < 32; i += 8)
    out[(long)(bx + i) * L_ + by + tx] = t[tx][i];
}

// In-place softmax over rows of length rowlen, bf16. One block per row.
__global__ void softmax_rows(u16* __restrict__ data, int rowlen)
{
  const long base = (long)blockIdx.x * rowlen;
  const int tid = threadIdx.x, wave = tid >> 6, lane = tid & 63;
  __shared__ float red[4];

  float m = -3.4e38f;
  for (int i = tid; i < rowlen; i += 256) m = fmaxf(m, bf2f(data[base + i]));
#pragma unroll
  for (int off = 32; off; off >>= 1) m = fmaxf(m, __shfl_xor(m, off, 64));
  if (lane == 0) red[wave] = m;
  __syncthreads();
  m = fmaxf(fmaxf(red[0], red[1]), fmaxf(red[2], red[3]));
  __syncthreads();

  float s = 0.f;
  for (int i = tid; i < rowlen; i += 256) s += expf(bf2f(data[base + i]) - m);
#pragma unroll
  for (int off = 32; off; off >>= 1) s += __shfl_xor(s, off, 64);
  if (lane == 0) red[wave] = s;
  __syncthreads();
  const float inv = 1.f / (red[0] + red[1] + red[2] + red[3]);
  for (int i = tid; i < rowlen; i += 256)
    data[base + i] = f2bf(expf(bf2f(data[base + i]) - m) * inv);
}

// ---------------------------------------------------------------------------
extern "C" void kernel_launch(void* const* d_in, const int* in_sizes, int n_in,
                              void* d_out, int out_size, void* d_ws, size_t ws_size,
                              hipStream_t stream)
{
  const float* source = (const float*)d_in[0];
  const float* target = (const float*)d_in[1];
  const float* Wq     = (const float*)d_in[2];
  const float* Wk     = (const float*)d_in[3];
  const float* Wv     = (const float*)d_in[4];
  const float* Wl     = (const float*)d_in[5];
  const float* gamma1 = (const float*)d_in[6];
  const float* beta1  = (const float*)d_in[7];
  const float* W1     = (const float*)d_in[8];
  const float* b1     = (const float*)d_in[9];
  const float* W2     = (const float*)d_in[10];
  const float* b2     = (const float*)d_in[11];
  const float* gamma2 = (const float*)d_in[12];
  const float* beta2  = (const float*)d_in[13];
  (void)in_sizes; (void)n_in; (void)out_size;

  char* ws = (char*)d_ws;
  size_t off = 0;
  auto take = [&](size_t bytes) -> char* {
    char* p = ws + off; off += (bytes + 255) & ~(size_t)255; return p;
  };
  // fixed region (live through FFN)
  u16*   WqkvT = (u16*)take((size_t)768 * C_ * 2);   // [ql|k|v] weights, NxK
  u16*   WqC   = (u16*)take((size_t)C_ * C_ * 2);    // Wq cast (d,e)
  u16*   WlT   = (u16*)take((size_t)C_ * C_ * 2);
  u16*   W1T   = (u16*)take((size_t)FFN_ * 512 * 2);
  u16*   W2T   = (u16*)take((size_t)C_ * FFN_ * 2);
  float* Mtf   = (float*)take((size_t)B_ * C_ * C_ * 4);
  u16*   srcB  = (u16*)take((size_t)BLC_ * 2);
  u16*   msg   = (u16*)take((size_t)BLC_ * 2);
  const size_t ubase = off;
  // pool region (dead before FFN; hidden overlays it)
  u16*   tgtB  = (u16*)take((size_t)BLC_ * 2);
  u16*   QKV   = (u16*)take((size_t)BL_ * 768 * 2);
  u16*   qlT   = (u16*)take((size_t)BLC_ * 2);
  u16*   kT    = (u16*)take((size_t)BLC_ * 2);
  const size_t pool = off - ubase;
  u16*   hidden = (u16*)(ws + ubase);

  int nchunk = 1;
  for (; nchunk < 8; nchunk <<= 1) {
    size_t hid = ((size_t)BL_ / nchunk) * FFN_ * 2;
    size_t need = ubase + (hid > pool ? hid : pool);
    if (need <= ws_size) break;
  }
  const int Mc = BL_ / nchunk;

  dim3 tb(32, 8);
  weightpack<<<1792, tb, 0, stream>>>(Wq, Wk, Wv, Wl, W1, W2, WqC, WlT, WqkvT, W1T, W2T);
  castzero<<<dim3(BLC_ / 1024 + (B_ * C_ * C_) / 1024, 2), 256, 0, stream>>>(
      source, target, srcB, tgtB, Mtf);

  // Wql^T[c,d] = sum_e Wl[e,c] * Wq[d,e]  -> q-slot of WqkvT (tiny GEMM)
  gemm_abt<0,0,0><<<4, 256, 0, stream>>>(
      WlT, WlT, 0, C_, WqC, nullptr, WqkvT, nullptr, C_, C_, C_, 0, 0, 0);

  // [ql|k|v] = [src|tgt|tgt] @ [Wql|Wk|Wv]   (N-switch at 256)
  gemm_abt<2,0,0><<<(BL_/128)*(768/128), 256, 0, stream>>>(
      srcB, tgtB, 256, C_, WqkvT, nullptr, QKV, nullptr, BL_, 768, C_, 0, 0, 0);

  transQK<<<dim3(8, L_/32, 8), tb, 0, stream>>>(QKV, qlT, kT);
  softmax_rows<<<B_*C_, 256, 0, stream>>>(kT, L_);

  // Mt[c,e] = sum_n qlT[c,n] * ksmT[e,n]  (split-K over tokens, fp32 atomics)
  gemm_abt<0,0,1><<<dim3(4, 16, B_), 256, 0, stream>>>(
      qlT, qlT, 0, L_, kT, nullptr, nullptr, Mtf, C_, C_, L_,
      (long)C_*L_, (long)C_*L_, (long)C_*C_);

  // message = LN1( v @ Mt^T )   (v strided in QKV; Mt staged fp32->bf16)
  gemm_ln<1,0><<<BL_/64, 256, 0, stream>>>(
      QKV + 512, (long)L_*768, 768, 256, Mtf, (long)C_*C_, 13,
      nullptr, gamma1, beta1, nullptr, msg, 0);

  // FFN: hidden = gelu([src|msg]@W1+b1); out = src + LN2(hidden@W2+b2)
  for (int ch = 0; ch < nchunk; ch++) {
    const long moff = (long)ch * Mc;
    gemm_abt<1,1,0><<<(Mc/128)*(FFN_/128), 256, 0, stream>>>(
        srcB + moff * C_, msg + moff * C_, 256, C_, W1T, b1, hidden, nullptr,
        Mc, FFN_, 512, 0, 0, 0);
    gemm_ln<0,1><<<Mc/64, 256, 0, stream>>>(
        hidden, 0, FFN_, FFN_, W2T, 0, 30,
        b2, gamma2, beta2, source, d_out, moff);
  }
}